// Round 4
// baseline (1101.193 us; speedup 1.0000x reference)
//
#include <hip/hip_runtime.h>
#include <hip/hip_bf16.h>

#define N_NODES 100000
#define M_PAD   100096   // 782 * 128
#define FDIM    512
#define N_EDGES 3200000
#define GEMM_BLOCKS 3128 // 782 * 4
#define GEMM_MAIN   3104 // 97 * 32 (full swizzle groups)

// ---- two-level counting sort geometry (no global atomics) ----
#define NB    782        // row buckets of 128 rows: ceil(100000/128) -> 3.05 blocks/CU in sort2
#define B1    782        // pass-1 slices: 782 * 4096 = 3,203,072 >= N_EDGES
#define SLICE 4096

typedef __attribute__((ext_vector_type(8))) short short8;          // 8 bf16 = 4 VGPRs (MFMA A/B frag)
typedef __attribute__((ext_vector_type(8))) unsigned short ushort8;
typedef __attribute__((ext_vector_type(4))) float floatx4;
typedef __attribute__((ext_vector_type(2))) int intx2;

__device__ __forceinline__ unsigned short f2bf(float f) {
    unsigned u = __float_as_uint(f);
    u += 0x7FFFu + ((u >> 16) & 1u);      // round-to-nearest-even
    return (unsigned short)(u >> 16);
}
__device__ __forceinline__ float bf2f(unsigned short u) {
    return __uint_as_float(((unsigned)u) << 16);
}

// ---- 1a. weight fp32 [K][N] -> bf16 transposed [N][K] ----
__global__ __launch_bounds__(256) void convert_w_k(const float* __restrict__ W,
                                                   unsigned short* __restrict__ Wt) {
    int idx = blockIdx.x * 256 + threadIdx.x;   // 0 .. 512*512-1
    int k = idx >> 9, n = idx & 511;
    Wt[n * 512 + k] = f2bf(W[idx]);
}

// ---- 1b. features fp32 -> bf16 ----
__global__ __launch_bounds__(256) void convert_a_k(const float* __restrict__ F,
                                                   unsigned short* __restrict__ Af) {
    int i = blockIdx.x * 256 + threadIdx.x;     // one thread per 8 floats
    if (i >= (N_NODES * FDIM) / 8) return;
    const float4* p = (const float4*)F + (size_t)i * 2;
    float4 a = p[0], b = p[1];
    ushort8 u = { f2bf(a.x), f2bf(a.y), f2bf(a.z), f2bf(a.w),
                  f2bf(b.x), f2bf(b.y), f2bf(b.z), f2bf(b.w) };
    *(ushort8*)(Af + (size_t)i * 8) = u;
}

// ---- 2. pass-1 histogram: per-slice LDS hist over 782 coarse buckets ----
__global__ __launch_bounds__(256) void hist1_k(const int* __restrict__ row,
                                               int* __restrict__ H) {   // H[b][NB]
    __shared__ int h[NB];
    const int b = blockIdx.x;
    for (int k = threadIdx.x; k < NB; k += 256) h[k] = 0;
    __syncthreads();
    const int base = b * SLICE;
    const int limit = min(base + SLICE, N_EDGES);
    for (int i = base + threadIdx.x; i < limit; i += 256)
        atomicAdd(&h[row[i] >> 7], 1);
    __syncthreads();
    for (int k = threadIdx.x; k < NB; k += 256)
        H[b * NB + k] = h[k];
}

// ---- 3a. scan H columns over slices (one block per bucket, in-place excl) ----
__global__ __launch_bounds__(1024) void scanA_k(int* __restrict__ H,
                                                int* __restrict__ totals) {
    __shared__ int sm[1024];
    const int k = blockIdx.x, tid = threadIdx.x;
    int v = (tid < B1) ? H[tid * NB + k] : 0;
    sm[tid] = v;
    __syncthreads();
    #pragma unroll
    for (int off = 1; off < 1024; off <<= 1) {
        int t = (tid >= off) ? sm[tid - off] : 0;
        __syncthreads();
        sm[tid] += t;
        __syncthreads();
    }
    if (tid < B1) H[tid * NB + k] = sm[tid] - v;   // exclusive over slices
    if (tid == B1 - 1) totals[k] = sm[tid];        // bucket total
}

// ---- 3b. exclusive scan of the 782 bucket totals ----
__global__ __launch_bounds__(1024) void scanB_k(const int* __restrict__ totals,
                                                int* __restrict__ start) {
    __shared__ int sm[1024];
    const int tid = threadIdx.x;
    int v = (tid < NB) ? totals[tid] : 0;
    sm[tid] = v;
    __syncthreads();
    #pragma unroll
    for (int off = 1; off < 1024; off <<= 1) {
        int t = (tid >= off) ? sm[tid - off] : 0;
        __syncthreads();
        sm[tid] += t;
        __syncthreads();
    }
    if (tid < NB) start[tid] = sm[tid] - v;
    if (tid == 0) start[NB] = N_EDGES;
}

// ---- 4. pass-1 scatter: append (col,val) + local row into bucket regions ----
__global__ __launch_bounds__(256) void scatter1_k(const int* __restrict__ row,
                                                  const int* __restrict__ col,
                                                  const float* __restrict__ val,
                                                  const int* __restrict__ H,
                                                  const int* __restrict__ start,
                                                  int2* __restrict__ tmp_cv,
                                                  unsigned char* __restrict__ tmp_r8) {
    __shared__ int cur[NB];
    const int b = blockIdx.x;
    for (int k = threadIdx.x; k < NB; k += 256)
        cur[k] = start[k] + H[b * NB + k];
    __syncthreads();
    const int base = b * SLICE;
    const int limit = min(base + SLICE, N_EDGES);
    for (int i = base + threadIdx.x; i < limit; i += 256) {
        int r = row[i];
        int p = atomicAdd(&cur[r >> 7], 1);          // LDS atomic
        tmp_cv[p] = make_int2(col[i], __float_as_int(val[i]));
        tmp_r8[p] = (unsigned char)(r & 127);
    }
}

// ---- 5. pass-2: sort each ~32KB bucket by local row, emit row_start + edges ----
__global__ __launch_bounds__(256) void sort2_k(const int* __restrict__ start,
                                               const int2* __restrict__ tmp_cv,
                                               const unsigned char* __restrict__ tmp_r8,
                                               int* __restrict__ row_start,
                                               int2* __restrict__ edges) {
    __shared__ int h[128];
    __shared__ int cur[128];
    const int k = blockIdx.x, tid = threadIdx.x;
    const int base = start[k], cnt = start[k + 1] - base;
    if (tid < 128) h[tid] = 0;
    __syncthreads();
    for (int i = tid; i < cnt; i += 256)
        atomicAdd(&h[tmp_r8[base + i]], 1);          // LDS atomic
    __syncthreads();
    int v = (tid < 128) ? h[tid] : 0;
    #pragma unroll
    for (int off = 1; off < 128; off <<= 1) {
        int t = (tid >= off && tid < 128) ? h[tid - off] : 0;
        __syncthreads();
        if (tid < 128) h[tid] += t;
        __syncthreads();
    }
    if (tid < 128) {
        int excl = h[tid] - v;
        int r = (k << 7) + tid;
        if (r < N_NODES) row_start[r] = base + excl;
        cur[tid] = base + excl;
    }
    if (k == NB - 1 && tid == 0) row_start[N_NODES] = N_EDGES;
    __syncthreads();
    for (int i = tid; i < cnt; i += 256) {
        unsigned char rl = tmp_r8[base + i];
        int p = atomicAdd(&cur[rl], 1);              // LDS atomic
        edges[p] = tmp_cv[base + i];
    }
}

// ---- 6. GEMM (m97 structure, BK=64): support[M][N] bf16 = Af[M][K] bf16 @ Wt[N][K]^T ----
// 128x128 tile, BK=64 (8 K-iters -> half the barrier drains of BK=32), 4 waves,
// 4x4 16x16 MFMA x2 k-halves per wave. Both operands via global_load_lds width-16.
// XCD swizzle: 4 col-blocks of one A row-panel on the same XCD.
__global__ __launch_bounds__(256) void gemm_k(const unsigned short* __restrict__ A,   // bf16 [M_PAD][K]
                                              const unsigned short* __restrict__ Bt,  // bf16 [N][K]
                                              unsigned short* __restrict__ C) {       // bf16 [M][N]
    const int id = blockIdx.x;
    int mb, nb;
    if (id < GEMM_MAIN) {                 // ids {c, c+8, c+16, c+24} within a 32-group
        mb = (id >> 5) * 8 + (id & 7);    //   share mb, cover nb = 0..3, same XCD
        nb = (id >> 3) & 3;
    } else {                              // tail: 6 row-panels, plain mapping
        int t = id - GEMM_MAIN;
        mb = 776 + (t >> 2);
        nb = t & 3;
    }
    const int baseM = mb * 128;
    const int baseN = nb * 128;
    const int tid  = threadIdx.x;
    const int lane = tid & 63, wave = tid >> 6;
    const int wm = (wave & 1) * 64;
    const int wn = (wave >> 1) * 64;
    const int lrow = lane & 15, quad = lane >> 4;

    __shared__ unsigned short As[128 * 64];      // linear [m][k], 16KB, global_load_lds dest
    __shared__ unsigned short Bs[128 * 64];      // linear [n][k], 16KB

    floatx4 acc[4][4] = {};

    for (int k0 = 0; k0 < FDIM; k0 += 64) {
        // stage 16KB per operand: 4 x 16B per thread each
        #pragma unroll
        for (int i = 0; i < 4; ++i) {
            int ofs = i * 4096 + tid * 16;       // byte offset in tile
            int row = ofs >> 7;                  // 128B per row
            int ke  = (ofs & 127) >> 1;          // element offset in row (0..63)
            __builtin_amdgcn_global_load_lds(
                (const __attribute__((address_space(1))) void*)
                    (A + (size_t)(baseM + row) * FDIM + k0 + ke),
                (__attribute__((address_space(3))) void*)((char*)As + ofs),
                16, 0, 0);
            __builtin_amdgcn_global_load_lds(
                (const __attribute__((address_space(1))) void*)
                    (Bt + (size_t)(baseN + row) * FDIM + k0 + ke),
                (__attribute__((address_space(3))) void*)((char*)Bs + ofs),
                16, 0, 0);
        }
        __syncthreads();

        short8 af[4][2], bfr[4][2];
        #pragma unroll
        for (int mi = 0; mi < 4; ++mi)
            #pragma unroll
            for (int kk = 0; kk < 2; ++kk)
                af[mi][kk] = *(const short8*)(As + (wm + mi * 16 + lrow) * 64 + kk * 32 + quad * 8);
        #pragma unroll
        for (int ni = 0; ni < 4; ++ni)
            #pragma unroll
            for (int kk = 0; kk < 2; ++kk)
                bfr[ni][kk] = *(const short8*)(Bs + (wn + ni * 16 + lrow) * 64 + kk * 32 + quad * 8);
        #pragma unroll
        for (int kk = 0; kk < 2; ++kk)
            #pragma unroll
            for (int mi = 0; mi < 4; ++mi)
                #pragma unroll
                for (int ni = 0; ni < 4; ++ni)
                    acc[mi][ni] = __builtin_amdgcn_mfma_f32_16x16x32_bf16(
                        af[mi][kk], bfr[ni][kk], acc[mi][ni], 0, 0, 0);
        __syncthreads();
    }

    // epilogue: C/D layout col=lane&15, row=quad*4+reg
    #pragma unroll
    for (int mi = 0; mi < 4; ++mi)
        #pragma unroll
        for (int ni = 0; ni < 4; ++ni)
            #pragma unroll
            for (int rr = 0; rr < 4; ++rr) {
                int row  = baseM + wm + mi * 16 + quad * 4 + rr;
                int colj = baseN + wn + ni * 16 + lrow;
                if (row < N_NODES)
                    C[(size_t)row * FDIM + colj] = f2bf(acc[mi][ni][rr]);
            }
}

// ---- 7. SpMM + ReLU: 4 waves per block, one row per wave, lane owns 8 features ----
// 25000 workgroups (vs 100000 1-wave ones): removes CP dispatch + workgroup-slot caps.
__global__ __launch_bounds__(256) void spmm_k(const unsigned short* __restrict__ sup,
                                              const int* __restrict__ row_start,
                                              const int2* __restrict__ edges,
                                              float* __restrict__ out) {
    const int r = blockIdx.x * 4 + (threadIdx.x >> 6);
    const int lane = threadIdx.x & 63;
    const int start = row_start[r], end = row_start[r + 1];
    const unsigned short* supl = sup + lane * 8;

    float acc[8] = {0.f, 0.f, 0.f, 0.f, 0.f, 0.f, 0.f, 0.f};

    const int n8 = (end - start) & ~7;
    for (int eb = start; eb < start + n8; eb += 8) {
        intx2 p[8];
        #pragma unroll
        for (int j = 0; j < 8; ++j)
            p[j] = __builtin_nontemporal_load((const intx2*)&edges[eb + j]);
        ushort8 s[8];
        #pragma unroll
        for (int j = 0; j < 8; ++j)
            s[j] = *(const ushort8*)(supl + (size_t)p[j].x * FDIM);
        #pragma unroll
        for (int j = 0; j < 8; ++j) {
            float v = __int_as_float(p[j].y);
            #pragma unroll
            for (int i = 0; i < 8; ++i)
                acc[i] += v * bf2f((unsigned short)s[j][i]);
        }
    }
    for (int e = start + n8; e < end; ++e) {
        intx2 p = __builtin_nontemporal_load((const intx2*)&edges[e]);
        ushort8 s = *(const ushort8*)(supl + (size_t)p.x * FDIM);
        float v = __int_as_float(p.y);
        #pragma unroll
        for (int i = 0; i < 8; ++i) acc[i] += v * bf2f((unsigned short)s[i]);
    }

    float* op = out + (size_t)r * FDIM + lane * 8;
    floatx4 o0 = { fmaxf(acc[0], 0.f), fmaxf(acc[1], 0.f),
                   fmaxf(acc[2], 0.f), fmaxf(acc[3], 0.f) };
    floatx4 o1 = { fmaxf(acc[4], 0.f), fmaxf(acc[5], 0.f),
                   fmaxf(acc[6], 0.f), fmaxf(acc[7], 0.f) };
    __builtin_nontemporal_store(o0, (floatx4*)op);
    __builtin_nontemporal_store(o1, (floatx4*)(op + 4));
}

extern "C" void kernel_launch(void* const* d_in, const int* in_sizes, int n_in,
                              void* d_out, int out_size, void* d_ws, size_t ws_size,
                              hipStream_t stream) {
    const float* features = (const float*)d_in[0];
    const float* weight   = (const float*)d_in[1];
    const int*   edge_row = (const int*)d_in[2];
    const int*   edge_col = (const int*)d_in[3];
    const float* edge_val = (const float*)d_in[4];
    float* out = (float*)d_out;

    char* ws = (char*)d_ws;
    size_t off = 0;
    unsigned short* sup = (unsigned short*)(ws + off); off += (size_t)N_NODES * FDIM * 2;  // 102.4 MB
    unsigned short* Af  = (unsigned short*)(ws + off); off += (size_t)M_PAD * FDIM * 2;    // 102.5 MB
    unsigned short* Wt  = (unsigned short*)(ws + off); off += (size_t)FDIM * FDIM * 2;     // 0.5 MB
    int* row_start = (int*)(ws + off); off += 400128;
    int2* edges    = (int2*)(ws + off); off += (size_t)N_EDGES * 8;                        // 25.6 MB
    // sort temporaries alias sup (dead until gemm_k writes it):
    char* supb = (char*)sup;
    int2* tmp_cv          = (int2*)(supb);                         // 25.6 MB
    unsigned char* tmp_r8 = (unsigned char*)(supb + 25600000);     // 3.2 MB
    int* H      = (int*)(supb + 28800000);                         // B1*NB*4 = 2.45 MB
    int* totals = (int*)(supb + 31246336);                         // 3.1 KB
    int* startb = (int*)(supb + 31250432);                         // 3.1 KB
    // total ws ≈ 231.4 MB

    convert_w_k<<<dim3((FDIM * FDIM) / 256), dim3(256), 0, stream>>>(weight, Wt);
    convert_a_k<<<dim3((N_NODES * FDIM / 8 + 255) / 256), dim3(256), 0, stream>>>(features, Af);
    hist1_k<<<dim3(B1), dim3(256), 0, stream>>>(edge_row, H);
    scanA_k<<<dim3(NB), dim3(1024), 0, stream>>>(H, totals);
    scanB_k<<<dim3(1), dim3(1024), 0, stream>>>(totals, startb);
    scatter1_k<<<dim3(B1), dim3(256), 0, stream>>>(edge_row, edge_col, edge_val,
                                                   H, startb, tmp_cv, tmp_r8);
    sort2_k<<<dim3(NB), dim3(256), 0, stream>>>(startb, tmp_cv, tmp_r8, row_start, edges);
    gemm_k<<<dim3(GEMM_BLOCKS), dim3(256), 0, stream>>>(Af, Wt, sup);
    spmm_k<<<dim3(N_NODES / 4), dim3(256), 0, stream>>>(sup, row_start, edges, out);
}

// Round 5
// 1069.042 us; speedup vs baseline: 1.0301x; 1.0301x over previous
//
#include <hip/hip_runtime.h>
#include <hip/hip_bf16.h>

#define N_NODES 100000
#define M_PAD   100096   // 782 * 128
#define FDIM    512
#define N_EDGES 3200000
#define GEMM_BLOCKS 3128 // 782 * 4
#define GEMM_MAIN   3104 // 97 * 32 (full swizzle groups)

// ---- two-level counting sort geometry (no global atomics), R3-proven ----
#define NB    391        // row buckets of 256 rows: ceil(100000/256)
#define B1    782        // pass-1 slices: 782 * 4096 = 3,203,072 >= N_EDGES
#define SLICE 4096

typedef __attribute__((ext_vector_type(8))) short short8;          // 8 bf16 = 4 VGPRs (MFMA A/B frag)
typedef __attribute__((ext_vector_type(8))) unsigned short ushort8;
typedef __attribute__((ext_vector_type(4))) float floatx4;
typedef __attribute__((ext_vector_type(2))) int intx2;

__device__ __forceinline__ unsigned short f2bf(float f) {
    unsigned u = __float_as_uint(f);
    u += 0x7FFFu + ((u >> 16) & 1u);      // round-to-nearest-even
    return (unsigned short)(u >> 16);
}
__device__ __forceinline__ float bf2f(unsigned short u) {
    return __uint_as_float(((unsigned)u) << 16);
}

// ---- 1a. weight fp32 [K][N] -> bf16 transposed [N][K] ----
__global__ __launch_bounds__(256) void convert_w_k(const float* __restrict__ W,
                                                   unsigned short* __restrict__ Wt) {
    int idx = blockIdx.x * 256 + threadIdx.x;   // 0 .. 512*512-1
    int k = idx >> 9, n = idx & 511;
    Wt[n * 512 + k] = f2bf(W[idx]);
}

// ---- 1b. features fp32 -> bf16 ----
__global__ __launch_bounds__(256) void convert_a_k(const float* __restrict__ F,
                                                   unsigned short* __restrict__ Af) {
    int i = blockIdx.x * 256 + threadIdx.x;     // one thread per 8 floats
    if (i >= (N_NODES * FDIM) / 8) return;
    const float4* p = (const float4*)F + (size_t)i * 2;
    float4 a = p[0], b = p[1];
    ushort8 u = { f2bf(a.x), f2bf(a.y), f2bf(a.z), f2bf(a.w),
                  f2bf(b.x), f2bf(b.y), f2bf(b.z), f2bf(b.w) };
    *(ushort8*)(Af + (size_t)i * 8) = u;
}

// ---- 2. pass-1 histogram: per-slice LDS hist over 391 coarse buckets ----
__global__ __launch_bounds__(256) void hist1_k(const int* __restrict__ row,
                                               int* __restrict__ H) {   // H[b][NB]
    __shared__ int h[NB];
    const int b = blockIdx.x;
    for (int k = threadIdx.x; k < NB; k += 256) h[k] = 0;
    __syncthreads();
    const int base = b * SLICE;
    const int limit = min(base + SLICE, N_EDGES);
    for (int i = base + threadIdx.x; i < limit; i += 256)
        atomicAdd(&h[row[i] >> 8], 1);
    __syncthreads();
    for (int k = threadIdx.x; k < NB; k += 256)
        H[b * NB + k] = h[k];
}

// ---- 3a. scan H columns over slices (one block per bucket, in-place excl) ----
__global__ __launch_bounds__(1024) void scanA_k(int* __restrict__ H,
                                                int* __restrict__ totals) {
    __shared__ int sm[1024];
    const int k = blockIdx.x, tid = threadIdx.x;
    int v = (tid < B1) ? H[tid * NB + k] : 0;
    sm[tid] = v;
    __syncthreads();
    #pragma unroll
    for (int off = 1; off < 1024; off <<= 1) {
        int t = (tid >= off) ? sm[tid - off] : 0;
        __syncthreads();
        sm[tid] += t;
        __syncthreads();
    }
    if (tid < B1) H[tid * NB + k] = sm[tid] - v;   // exclusive over slices
    if (tid == B1 - 1) totals[k] = sm[tid];        // bucket total
}

// ---- 3b. exclusive scan of the 391 bucket totals ----
__global__ __launch_bounds__(512) void scanB_k(const int* __restrict__ totals,
                                               int* __restrict__ start) {
    __shared__ int sm[512];
    const int tid = threadIdx.x;
    int v = (tid < NB) ? totals[tid] : 0;
    sm[tid] = v;
    __syncthreads();
    #pragma unroll
    for (int off = 1; off < 512; off <<= 1) {
        int t = (tid >= off) ? sm[tid - off] : 0;
        __syncthreads();
        sm[tid] += t;
        __syncthreads();
    }
    if (tid < NB) start[tid] = sm[tid] - v;
    if (tid == 0) start[NB] = N_EDGES;
}

// ---- 4. pass-1 scatter: append (col,val) + local row into bucket regions ----
__global__ __launch_bounds__(256) void scatter1_k(const int* __restrict__ row,
                                                  const int* __restrict__ col,
                                                  const float* __restrict__ val,
                                                  const int* __restrict__ H,
                                                  const int* __restrict__ start,
                                                  int2* __restrict__ tmp_cv,
                                                  unsigned char* __restrict__ tmp_r8) {
    __shared__ int cur[NB];
    const int b = blockIdx.x;
    for (int k = threadIdx.x; k < NB; k += 256)
        cur[k] = start[k] + H[b * NB + k];
    __syncthreads();
    const int base = b * SLICE;
    const int limit = min(base + SLICE, N_EDGES);
    for (int i = base + threadIdx.x; i < limit; i += 256) {
        int r = row[i];
        int p = atomicAdd(&cur[r >> 8], 1);          // LDS atomic
        tmp_cv[p] = make_int2(col[i], __float_as_int(val[i]));
        tmp_r8[p] = (unsigned char)(r & 255);
    }
}

// ---- 5. pass-2: sort each ~64KB bucket by local row, emit row_start + edges ----
__global__ __launch_bounds__(256) void sort2_k(const int* __restrict__ start,
                                               const int2* __restrict__ tmp_cv,
                                               const unsigned char* __restrict__ tmp_r8,
                                               int* __restrict__ row_start,
                                               int2* __restrict__ edges) {
    __shared__ int h[256];
    __shared__ int cur[256];
    const int k = blockIdx.x, tid = threadIdx.x;
    const int base = start[k], cnt = start[k + 1] - base;
    h[tid] = 0;
    __syncthreads();
    for (int i = tid; i < cnt; i += 256)
        atomicAdd(&h[tmp_r8[base + i]], 1);          // LDS atomic
    __syncthreads();
    int v = h[tid];
    #pragma unroll
    for (int off = 1; off < 256; off <<= 1) {
        int t = (tid >= off) ? h[tid - off] : 0;
        __syncthreads();
        h[tid] += t;
        __syncthreads();
    }
    int excl = h[tid] - v;
    int r = (k << 8) + tid;
    if (r < N_NODES) row_start[r] = base + excl;
    cur[tid] = base + excl;
    if (k == NB - 1 && tid == 0) row_start[N_NODES] = N_EDGES;
    __syncthreads();
    for (int i = tid; i < cnt; i += 256) {
        unsigned char rl = tmp_r8[base + i];
        int p = atomicAdd(&cur[rl], 1);              // LDS atomic
        edges[p] = tmp_cv[base + i];
    }
}

// ---- 6. GEMM (m97 structure, BK=64, LDS-staged coalesced epilogue) ----
// support[M][N] bf16 = Af[M][K] bf16 @ Wt[N][K]^T. 128x128 tile, 4 waves,
// both operands via global_load_lds width-16. XCD swizzle groups the 4
// col-blocks of one A row-panel on the same XCD.
// Epilogue: acc -> LDS (bf16, padded stride) -> uint4 coalesced stores
// (replaces 64 scalar 2B stores/thread with 8 vector stores/thread).
__global__ __launch_bounds__(256) void gemm_k(const unsigned short* __restrict__ A,   // bf16 [M_PAD][K]
                                              const unsigned short* __restrict__ Bt,  // bf16 [N][K]
                                              unsigned short* __restrict__ C) {       // bf16 [M][N]
    const int id = blockIdx.x;
    int mb, nb;
    if (id < GEMM_MAIN) {                 // ids {c, c+8, c+16, c+24} within a 32-group
        mb = (id >> 5) * 8 + (id & 7);    //   share mb, cover nb = 0..3, same XCD
        nb = (id >> 3) & 3;
    } else {                              // tail: 6 row-panels, plain mapping
        int t = id - GEMM_MAIN;
        mb = 776 + (t >> 2);
        nb = t & 3;
    }
    const int baseM = mb * 128;
    const int baseN = nb * 128;
    const int tid  = threadIdx.x;
    const int lane = tid & 63, wave = tid >> 6;
    const int wm = (wave & 1) * 64;
    const int wn = (wave >> 1) * 64;
    const int lrow = lane & 15, quad = lane >> 4;

    __shared__ unsigned short As[128 * 64];      // linear [m][k], 16KB, global_load_lds dest
    __shared__ unsigned short Bs[128 * 64];      // linear [n][k], 16KB (epilogue reuses)

    floatx4 acc[4][4] = {};

    for (int k0 = 0; k0 < FDIM; k0 += 64) {
        // stage 16KB per operand: 4 x 16B per thread each
        #pragma unroll
        for (int i = 0; i < 4; ++i) {
            int ofs = i * 4096 + tid * 16;       // byte offset in tile
            int row = ofs >> 7;                  // 128B per row
            int ke  = (ofs & 127) >> 1;          // element offset in row (0..63)
            __builtin_amdgcn_global_load_lds(
                (const __attribute__((address_space(1))) void*)
                    (A + (size_t)(baseM + row) * FDIM + k0 + ke),
                (__attribute__((address_space(3))) void*)((char*)As + ofs),
                16, 0, 0);
            __builtin_amdgcn_global_load_lds(
                (const __attribute__((address_space(1))) void*)
                    (Bt + (size_t)(baseN + row) * FDIM + k0 + ke),
                (__attribute__((address_space(3))) void*)((char*)Bs + ofs),
                16, 0, 0);
        }
        __syncthreads();

        short8 af[4][2], bfr[4][2];
        #pragma unroll
        for (int mi = 0; mi < 4; ++mi)
            #pragma unroll
            for (int kk = 0; kk < 2; ++kk)
                af[mi][kk] = *(const short8*)(As + (wm + mi * 16 + lrow) * 64 + kk * 32 + quad * 8);
        #pragma unroll
        for (int ni = 0; ni < 4; ++ni)
            #pragma unroll
            for (int kk = 0; kk < 2; ++kk)
                bfr[ni][kk] = *(const short8*)(Bs + (wn + ni * 16 + lrow) * 64 + kk * 32 + quad * 8);
        #pragma unroll
        for (int kk = 0; kk < 2; ++kk)
            #pragma unroll
            for (int mi = 0; mi < 4; ++mi)
                #pragma unroll
                for (int ni = 0; ni < 4; ++ni)
                    acc[mi][ni] = __builtin_amdgcn_mfma_f32_16x16x32_bf16(
                        af[mi][kk], bfr[ni][kk], acc[mi][ni], 0, 0, 0);
        __syncthreads();
    }

    // ---- epilogue: acc -> LDS bf16 -> coalesced uint4 stores ----
    // D layout: col = lane&15, row = quad*4 + rr. Per mi-round the 4 waves
    // cover a 32-row x 128-col stripe (rows {mi*16..} and {64+mi*16..}).
    unsigned short* Ls = Bs;                     // 32 x 136 bf16 = 8.7 KB staging
    const int erow = (wave & 1) * 16 + quad * 4; // local row base in stripe
    #pragma unroll
    for (int mi = 0; mi < 4; ++mi) {
        __syncthreads();                         // previous round's reads done
        #pragma unroll
        for (int ni = 0; ni < 4; ++ni)
            #pragma unroll
            for (int rr = 0; rr < 4; ++rr)
                Ls[(erow + rr) * 136 + wn + ni * 16 + lrow] = f2bf(acc[mi][ni][rr]);
        __syncthreads();
        #pragma unroll
        for (int it = 0; it < 2; ++it) {
            int q  = tid + it * 256;             // 0..511 chunks of 16B
            int rl = q >> 4;                     // 0..31 local row
            int gr = baseM + ((rl & 16) ? 64 : 0) + mi * 16 + (rl & 15);
            if (gr < N_NODES) {
                uint4 v = *(const uint4*)(Ls + rl * 136 + (q & 15) * 8);
                *(uint4*)(C + (size_t)gr * FDIM + baseN + (q & 15) * 8) = v;
            }
        }
    }
}

// ---- 7. SpMM + ReLU: 4 waves per block, one row per wave, lane owns 8 features ----
__global__ __launch_bounds__(256) void spmm_k(const unsigned short* __restrict__ sup,
                                              const int* __restrict__ row_start,
                                              const int2* __restrict__ edges,
                                              float* __restrict__ out) {
    const int r = blockIdx.x * 4 + (threadIdx.x >> 6);
    const int lane = threadIdx.x & 63;
    const int start = row_start[r], end = row_start[r + 1];
    const unsigned short* supl = sup + lane * 8;

    float acc[8] = {0.f, 0.f, 0.f, 0.f, 0.f, 0.f, 0.f, 0.f};

    const int n8 = (end - start) & ~7;
    for (int eb = start; eb < start + n8; eb += 8) {
        intx2 p[8];
        #pragma unroll
        for (int j = 0; j < 8; ++j)
            p[j] = __builtin_nontemporal_load((const intx2*)&edges[eb + j]);
        ushort8 s[8];
        #pragma unroll
        for (int j = 0; j < 8; ++j)
            s[j] = *(const ushort8*)(supl + (size_t)p[j].x * FDIM);
        #pragma unroll
        for (int j = 0; j < 8; ++j) {
            float v = __int_as_float(p[j].y);
            #pragma unroll
            for (int i = 0; i < 8; ++i)
                acc[i] += v * bf2f((unsigned short)s[j][i]);
        }
    }
    for (int e = start + n8; e < end; ++e) {
        intx2 p = __builtin_nontemporal_load((const intx2*)&edges[e]);
        ushort8 s = *(const ushort8*)(supl + (size_t)p.x * FDIM);
        float v = __int_as_float(p.y);
        #pragma unroll
        for (int i = 0; i < 8; ++i) acc[i] += v * bf2f((unsigned short)s[i]);
    }

    float* op = out + (size_t)r * FDIM + lane * 8;
    floatx4 o0 = { fmaxf(acc[0], 0.f), fmaxf(acc[1], 0.f),
                   fmaxf(acc[2], 0.f), fmaxf(acc[3], 0.f) };
    floatx4 o1 = { fmaxf(acc[4], 0.f), fmaxf(acc[5], 0.f),
                   fmaxf(acc[6], 0.f), fmaxf(acc[7], 0.f) };
    __builtin_nontemporal_store(o0, (floatx4*)op);
    __builtin_nontemporal_store(o1, (floatx4*)(op + 4));
}

extern "C" void kernel_launch(void* const* d_in, const int* in_sizes, int n_in,
                              void* d_out, int out_size, void* d_ws, size_t ws_size,
                              hipStream_t stream) {
    const float* features = (const float*)d_in[0];
    const float* weight   = (const float*)d_in[1];
    const int*   edge_row = (const int*)d_in[2];
    const int*   edge_col = (const int*)d_in[3];
    const float* edge_val = (const float*)d_in[4];
    float* out = (float*)d_out;

    char* ws = (char*)d_ws;
    size_t off = 0;
    unsigned short* sup = (unsigned short*)(ws + off); off += (size_t)N_NODES * FDIM * 2;  // 102.4 MB
    unsigned short* Af  = (unsigned short*)(ws + off); off += (size_t)M_PAD * FDIM * 2;    // 102.5 MB
    unsigned short* Wt  = (unsigned short*)(ws + off); off += (size_t)FDIM * FDIM * 2;     // 0.5 MB
    int* row_start = (int*)(ws + off); off += 400128;
    int2* edges    = (int2*)(ws + off); off += (size_t)N_EDGES * 8;                        // 25.6 MB
    // sort temporaries alias sup (dead until gemm_k writes it):
    char* supb = (char*)sup;
    int2* tmp_cv          = (int2*)(supb);                         // 25.6 MB
    unsigned char* tmp_r8 = (unsigned char*)(supb + 25600000);     // 3.2 MB
    int* H      = (int*)(supb + 28800000);                         // B1*NB*4 = 1.22 MB
    int* totals = (int*)(supb + 30026240);                         // 1.6 KB
    int* startb = (int*)(supb + 30030336);                         // 1.6 KB
    // total ws ≈ 231.4 MB

    convert_w_k<<<dim3((FDIM * FDIM) / 256), dim3(256), 0, stream>>>(weight, Wt);
    convert_a_k<<<dim3((N_NODES * FDIM / 8 + 255) / 256), dim3(256), 0, stream>>>(features, Af);
    hist1_k<<<dim3(B1), dim3(256), 0, stream>>>(edge_row, H);
    scanA_k<<<dim3(NB), dim3(1024), 0, stream>>>(H, totals);
    scanB_k<<<dim3(1), dim3(512), 0, stream>>>(totals, startb);
    scatter1_k<<<dim3(B1), dim3(256), 0, stream>>>(edge_row, edge_col, edge_val,
                                                   H, startb, tmp_cv, tmp_r8);
    sort2_k<<<dim3(NB), dim3(256), 0, stream>>>(startb, tmp_cv, tmp_r8, row_start, edges);
    gemm_k<<<dim3(GEMM_BLOCKS), dim3(256), 0, stream>>>(Af, Wt, sup);
    spmm_k<<<dim3(N_NODES / 4), dim3(256), 0, stream>>>(sup, row_start, edges, out);
}